// Round 7
// baseline (820.611 us; speedup 1.0000x reference)
//
#include <hip/hip_runtime.h>
#include <hip/hip_bf16.h>

// Problem constants: B=4, S=1024, F=1024, E=8, K=2, H=4*F=4096
constexpr int Ff = 1024;
constexpr int Ee = 8;
constexpr int Hh = 4096;
constexpr int T  = 4096;        // B*S tokens
constexpr int MB = 72;          // max 128-row m-blocks over padded row space

typedef short     bf16x8 __attribute__((ext_vector_type(8)));
typedef float     f32x4  __attribute__((ext_vector_type(4)));
typedef unsigned short u16x8 __attribute__((ext_vector_type(8)));

__device__ __forceinline__ float gelu_tanh(float v) {
  const float c = 0.7978845608028654f;  // sqrt(2/pi)
  float t = tanhf(c * (v + 0.044715f * v * v * v));
  return 0.5f * v * (1.0f + t);
}

__device__ __forceinline__ unsigned short bf16bits(float f) {
  __hip_bfloat16 h = __float2bfloat16(f);
  return *reinterpret_cast<unsigned short*>(&h);
}

// ---------------- Gating (fp32, exact routing) ----------------
__global__ __launch_bounds__(256) void gating_kernel(
    const float* __restrict__ x, const float* __restrict__ Wg,
    const float* __restrict__ bg, int* __restrict__ cnt,
    int* __restrict__ list, float* __restrict__ wlist) {
  const int wave = threadIdx.x >> 6;
  const int lane = threadIdx.x & 63;
  const int t = blockIdx.x * 4 + wave;
  float acc[Ee] = {0.f,0.f,0.f,0.f,0.f,0.f,0.f,0.f};
  const float* xrow = x + (size_t)t * Ff;
  for (int f0 = 0; f0 < Ff; f0 += 64) {
    float xv = xrow[f0 + lane];
    const float* wrow = Wg + (size_t)(f0 + lane) * Ee;
    float4 w0 = *reinterpret_cast<const float4*>(wrow);
    float4 w1 = *reinterpret_cast<const float4*>(wrow + 4);
    acc[0] += xv * w0.x; acc[1] += xv * w0.y;
    acc[2] += xv * w0.z; acc[3] += xv * w0.w;
    acc[4] += xv * w1.x; acc[5] += xv * w1.y;
    acc[6] += xv * w1.z; acc[7] += xv * w1.w;
  }
#pragma unroll
  for (int e = 0; e < Ee; ++e) {
#pragma unroll
    for (int off = 32; off; off >>= 1) acc[e] += __shfl_xor(acc[e], off);
  }
  if (lane == 0) {
    float l[Ee], m = -1e30f;
#pragma unroll
    for (int e = 0; e < Ee; ++e) { l[e] = acc[e] + bg[e]; m = fmaxf(m, l[e]); }
    float p[Ee], Z = 0.f;
#pragma unroll
    for (int e = 0; e < Ee; ++e) { p[e] = expf(l[e] - m); Z += p[e]; }
#pragma unroll
    for (int e = 0; e < Ee; ++e) p[e] /= Z;
    int i1 = 0; float p1 = p[0];
#pragma unroll
    for (int e = 1; e < Ee; ++e) if (p[e] > p1) { p1 = p[e]; i1 = e; }
    int i2 = -1; float p2 = -1e30f;
#pragma unroll
    for (int e = 0; e < Ee; ++e) if (e != i1 && p[e] > p2) { p2 = p[e]; i2 = e; }
    float denom = p1 + p2 + 1e-8f;
    int pos = atomicAdd(&cnt[i1], 1);
    list[i1 * T + pos] = t; wlist[i1 * T + pos] = p1 / denom;
    pos = atomicAdd(&cnt[i2], 1);
    list[i2 * T + pos] = t; wlist[i2 * T + pos] = p2 / denom;
  }
}

// 128-aligned expert row offsets (padded flattened row space)
__global__ void prefix_kernel(const int* __restrict__ cnt, int* __restrict__ offs) {
  if (threadIdx.x == 0) {
    int s = 0;
    for (int e = 0; e < Ee; ++e) { offs[e] = s; s += (cnt[e] + 127) & ~127; }
    offs[Ee] = s;
  }
}

// ---------------- x fp32 -> bf16 ----------------
__global__ __launch_bounds__(256) void cvt_x_kernel(
    const float* __restrict__ x, unsigned short* __restrict__ xb) {
  const size_t i = ((size_t)blockIdx.x * 256 + threadIdx.x) * 8;
  float4 a = *reinterpret_cast<const float4*>(x + i);
  float4 b = *reinterpret_cast<const float4*>(x + i + 4);
  u16x8 o;
  o[0] = bf16bits(a.x); o[1] = bf16bits(a.y); o[2] = bf16bits(a.z); o[3] = bf16bits(a.w);
  o[4] = bf16bits(b.x); o[5] = bf16bits(b.y); o[6] = bf16bits(b.z); o[7] = bf16bits(b.w);
  *reinterpret_cast<u16x8*>(xb + i) = o;
}

// -------- transpose + convert: dst[e][col][row] (bf16) = src[e][row][col] (fp32) --------
__global__ __launch_bounds__(256) void transpose_cvt_kernel(
    const float* __restrict__ src, unsigned short* __restrict__ dst,
    int s_rstride, int d_rstride, size_t s_estride, size_t d_estride) {
  const int e  = blockIdx.z;
  const int r0 = blockIdx.y * 64;
  const int c0 = blockIdx.x * 64;
  __shared__ __align__(16) unsigned short Ts[64][72];
  const int t = threadIdx.x;
  const float* sb = src + (size_t)e * s_estride + (size_t)r0 * s_rstride + c0;
  {
    const int rr = t >> 4;
    const int cc = (t & 15) * 4;
#pragma unroll
    for (int i = 0; i < 4; ++i) {
      float4 v = *reinterpret_cast<const float4*>(sb + (size_t)(rr + i * 16) * s_rstride + cc);
      Ts[cc + 0][rr + i * 16] = bf16bits(v.x);
      Ts[cc + 1][rr + i * 16] = bf16bits(v.y);
      Ts[cc + 2][rr + i * 16] = bf16bits(v.z);
      Ts[cc + 3][rr + i * 16] = bf16bits(v.w);
    }
  }
  __syncthreads();
  {
    const int n  = t >> 2;
    const int ks = (t & 3) * 16;
    unsigned short* db = dst + (size_t)e * d_estride + (size_t)(c0 + n) * d_rstride + r0 + ks;
    *reinterpret_cast<ulonglong2*>(db)     = *reinterpret_cast<const ulonglong2*>(&Ts[n][ks]);
    *reinterpret_cast<ulonglong2*>(db + 8) = *reinterpret_cast<const ulonglong2*>(&Ts[n][ks + 8]);
  }
}

// ======== GEMM1: h = gelu(xb[tokens] @ W1T^T + b1) — reg-direct, no LDS ========
// block = 128x128 (2x2 waves of 64x64); K-step 32; 2-deep register pipeline.
__global__ __launch_bounds__(256, 3) void gemm1_mfma(
    const unsigned short* __restrict__ xb, const unsigned short* __restrict__ W1T,
    const float* __restrict__ b1, const int* __restrict__ cnt,
    const int* __restrict__ offs, const int* __restrict__ list,
    unsigned short* __restrict__ h, int Hc, int c) {
  const int nxg = Hc >> 7;                 // n-blocks
  const int nwg = nxg * MB;
  int raw = blockIdx.x + nxg * blockIdx.y;
  int bid = (raw & 7) * (nwg >> 3) + (raw >> 3);
  const int by = bid % MB;                 // m fastest within XCD chunk -> B-panel L2 reuse
  const int bx = bid / MB;

  const int m0g = by * 128;
  int e = 0;
#pragma unroll
  for (int i = 1; i < Ee; ++i) e += (m0g >= offs[i]) ? 1 : 0;
  const int ce = cnt[e];
  const int mloc = m0g - offs[e];
  if (mloc >= ce) return;
  const int n0 = bx * 128;

  const int tid = threadIdx.x;
  const int w = tid >> 6, lane = tid & 63;
  const int g = lane >> 4, r16 = lane & 15;
  const int wm = w >> 1, wn = w & 1;

  // per-lane row base pointers (element offsets include k-slice g*8)
  const unsigned short* aPtr[4];
  const unsigned short* bPtr[4];
#pragma unroll
  for (int m = 0; m < 4; ++m) {
    const int mr = mloc + wm * 64 + m * 16 + r16;
    const int tok = (mr < ce) ? list[e * T + mr] : 0;
    aPtr[m] = xb + (size_t)tok * Ff + g * 8;
  }
#pragma unroll
  for (int n = 0; n < 4; ++n) {
    const int col = n0 + wn * 64 + n * 16 + r16;
    bPtr[n] = W1T + (size_t)e * Hc * Ff + (size_t)col * Ff + g * 8;
  }

  f32x4 acc[4][4] = {};
  constexpr int NT = Ff / 32;   // 32 (even)

  bf16x8 fA0[4], fB0[4], fA1[4], fB1[4];
#pragma unroll
  for (int m = 0; m < 4; ++m) fA0[m] = *reinterpret_cast<const bf16x8*>(aPtr[m]);
#pragma unroll
  for (int n = 0; n < 4; ++n) fB0[n] = *reinterpret_cast<const bf16x8*>(bPtr[n]);

#pragma unroll 1
  for (int kt = 0; kt + 2 <= NT; kt += 2) {
    const int ko1 = (kt + 1) * 32;
#pragma unroll
    for (int m = 0; m < 4; ++m) fA1[m] = *reinterpret_cast<const bf16x8*>(aPtr[m] + ko1);
#pragma unroll
    for (int n = 0; n < 4; ++n) fB1[n] = *reinterpret_cast<const bf16x8*>(bPtr[n] + ko1);
#pragma unroll
    for (int m = 0; m < 4; ++m)
#pragma unroll
      for (int n = 0; n < 4; ++n)
        acc[m][n] = __builtin_amdgcn_mfma_f32_16x16x32_bf16(fA0[m], fB0[n], acc[m][n], 0, 0, 0);
    if (kt + 2 < NT) {
      const int ko2 = (kt + 2) * 32;
#pragma unroll
      for (int m = 0; m < 4; ++m) fA0[m] = *reinterpret_cast<const bf16x8*>(aPtr[m] + ko2);
#pragma unroll
      for (int n = 0; n < 4; ++n) fB0[n] = *reinterpret_cast<const bf16x8*>(bPtr[n] + ko2);
    }
#pragma unroll
    for (int m = 0; m < 4; ++m)
#pragma unroll
      for (int n = 0; n < 4; ++n)
        acc[m][n] = __builtin_amdgcn_mfma_f32_16x16x32_bf16(fA1[m], fB1[n], acc[m][n], 0, 0, 0);
  }

#pragma unroll
  for (int n = 0; n < 4; ++n) {
    const int col = n0 + wn * 64 + n * 16 + r16;
    const float bias = b1[(size_t)e * Hh + (size_t)c * Hc + col];
#pragma unroll
    for (int m = 0; m < 4; ++m)
#pragma unroll
      for (int r = 0; r < 4; ++r) {
        const int row = wm * 64 + m * 16 + g * 4 + r;
        if (mloc + row < ce)
          h[(size_t)(m0g + row) * Hc + col] = bf16bits(gelu_tanh(acc[m][n][r] + bias));
      }
  }
}

// ==== GEMM2: out[token] += w * (h @ W2T^T (+b2)) — reg-direct, no LDS, K-split ====
__global__ __launch_bounds__(256, 3) void gemm2_mfma(
    const unsigned short* __restrict__ h, const unsigned short* __restrict__ W2T,
    const float* __restrict__ b2, const int* __restrict__ cnt,
    const int* __restrict__ offs, const int* __restrict__ list,
    const float* __restrict__ wlist, float* __restrict__ out,
    int Hc, int kLen, int biasC) {
  const int nxg = Ff >> 7;                 // 8
  const int nzg = Hc / kLen;
  const int nwg = nxg * MB * nzg;
  int raw = blockIdx.x + nxg * (blockIdx.y + MB * blockIdx.z);
  int bid = (raw & 7) * (nwg >> 3) + (raw >> 3);
  const int by = bid % MB;
  const int rest = bid / MB;
  const int bx = rest % nxg;
  const int bz = rest / nxg;
  const int kOff = bz * kLen;

  const int m0g = by * 128;
  int e = 0;
#pragma unroll
  for (int i = 1; i < Ee; ++i) e += (m0g >= offs[i]) ? 1 : 0;
  const int ce = cnt[e];
  const int mloc = m0g - offs[e];
  if (mloc >= ce) return;
  const int n0 = bx * 128;

  const int tid = threadIdx.x;
  const int w = tid >> 6, lane = tid & 63;
  const int g = lane >> 4, r16 = lane & 15;
  const int wm = w >> 1, wn = w & 1;

  const unsigned short* aPtr[4];
  const unsigned short* bPtr[4];
#pragma unroll
  for (int m = 0; m < 4; ++m) {
    const int row = m0g + wm * 64 + m * 16 + r16;   // padded h rows always valid
    aPtr[m] = h + (size_t)row * Hc + kOff + g * 8;
  }
#pragma unroll
  for (int n = 0; n < 4; ++n) {
    const int col = n0 + wn * 64 + n * 16 + r16;
    bPtr[n] = W2T + (size_t)e * Ff * Hc + (size_t)col * Hc + kOff + g * 8;
  }

  f32x4 acc[4][4] = {};
  const int NT = kLen / 32;   // >= 2, even

  bf16x8 fA0[4], fB0[4], fA1[4], fB1[4];
#pragma unroll
  for (int m = 0; m < 4; ++m) fA0[m] = *reinterpret_cast<const bf16x8*>(aPtr[m]);
#pragma unroll
  for (int n = 0; n < 4; ++n) fB0[n] = *reinterpret_cast<const bf16x8*>(bPtr[n]);

#pragma unroll 1
  for (int kt = 0; kt + 2 <= NT; kt += 2) {
    const int ko1 = (kt + 1) * 32;
#pragma unroll
    for (int m = 0; m < 4; ++m) fA1[m] = *reinterpret_cast<const bf16x8*>(aPtr[m] + ko1);
#pragma unroll
    for (int n = 0; n < 4; ++n) fB1[n] = *reinterpret_cast<const bf16x8*>(bPtr[n] + ko1);
#pragma unroll
    for (int m = 0; m < 4; ++m)
#pragma unroll
      for (int n = 0; n < 4; ++n)
        acc[m][n] = __builtin_amdgcn_mfma_f32_16x16x32_bf16(fA0[m], fB0[n], acc[m][n], 0, 0, 0);
    if (kt + 2 < NT) {
      const int ko2 = (kt + 2) * 32;
#pragma unroll
      for (int m = 0; m < 4; ++m) fA0[m] = *reinterpret_cast<const bf16x8*>(aPtr[m] + ko2);
#pragma unroll
      for (int n = 0; n < 4; ++n) fB0[n] = *reinterpret_cast<const bf16x8*>(bPtr[n] + ko2);
    }
#pragma unroll
    for (int m = 0; m < 4; ++m)
#pragma unroll
      for (int n = 0; n < 4; ++n)
        acc[m][n] = __builtin_amdgcn_mfma_f32_16x16x32_bf16(fA1[m], fB1[n], acc[m][n], 0, 0, 0);
  }

  const bool addBias = (biasC != 0) && (bz == 0);
#pragma unroll
  for (int m = 0; m < 4; ++m)
#pragma unroll
    for (int r = 0; r < 4; ++r) {
      const int row = wm * 64 + m * 16 + g * 4 + r;
      if (mloc + row >= ce) continue;
      const int token = list[e * T + mloc + row];
      const float wgt = wlist[e * T + mloc + row];
      float* op = out + (size_t)token * Ff;
#pragma unroll
      for (int n = 0; n < 4; ++n) {
        const int col = n0 + wn * 64 + n * 16 + r16;
        float v = acc[m][n][r];
        if (addBias) v += b2[(size_t)e * Ff + col];
        atomicAdd(&op[col], wgt * v);
      }
    }
}

extern "C" void kernel_launch(void* const* d_in, const int* in_sizes, int n_in,
                              void* d_out, int out_size, void* d_ws, size_t ws_size,
                              hipStream_t stream) {
  const float* x  = (const float*)d_in[0];
  const float* Wg = (const float*)d_in[1];
  const float* bg = (const float*)d_in[2];
  const float* W1 = (const float*)d_in[3];
  const float* b1 = (const float*)d_in[4];
  const float* W2 = (const float*)d_in[5];
  const float* b2 = (const float*)d_in[6];
  float* out = (float*)d_out;

  // Adaptive H-chunk. fixed = lists + xb; per-Hc-unit = W1T + W2T + h(9216 rows)
  const size_t fixed = 1024 + 2 * (size_t)T * Ee * 4 + (size_t)T * Ff * 2;
  int Hc = 4096;
  while (Hc > 256 && fixed + (size_t)Hc * 51200 > ws_size) Hc >>= 1;
  const int nchunk = Hh / Hc;
  const int ksplit = 4;
  const int kLen = Hc / ksplit;   // >= 64

  char* p = (char*)d_ws;
  int*   cnt   = (int*)p;            p += 512;
  int*   offs  = (int*)p;            p += 512;
  int*   list  = (int*)p;            p += (size_t)T * Ee * 4;
  float* wlist = (float*)p;          p += (size_t)T * Ee * 4;
  unsigned short* xb  = (unsigned short*)p;  p += (size_t)T * Ff * 2;
  unsigned short* W1T = (unsigned short*)p;  p += (size_t)Ee * Hc * Ff * 2;
  unsigned short* W2T = (unsigned short*)p;  p += (size_t)Ee * Ff * Hc * 2;
  unsigned short* h   = (unsigned short*)p;  // 9216 * Hc * 2

  hipMemsetAsync(d_out, 0, (size_t)out_size * sizeof(float), stream);
  hipMemsetAsync(cnt, 0, 64, stream);

  gating_kernel<<<T / 4, 256, 0, stream>>>(x, Wg, bg, cnt, list, wlist);
  prefix_kernel<<<1, 64, 0, stream>>>(cnt, offs);
  cvt_x_kernel<<<(T * Ff) / 2048, 256, 0, stream>>>(x, xb);

  for (int c = 0; c < nchunk; ++c) {
    transpose_cvt_kernel<<<dim3(Hc / 64, Ff / 64, Ee), 256, 0, stream>>>(
        W1 + (size_t)c * Hc, W1T, Hh, Ff, (size_t)Ff * Hh, (size_t)Hc * Ff);
    transpose_cvt_kernel<<<dim3(Ff / 64, Hc / 64, Ee), 256, 0, stream>>>(
        W2 + (size_t)c * Hc * Ff, W2T, Ff, Hc, (size_t)Hh * Ff, (size_t)Ff * Hc);
    gemm1_mfma<<<dim3(Hc / 128, MB), 256, 0, stream>>>(
        xb, W1T, b1, cnt, offs, list, h, Hc, c);
    gemm2_mfma<<<dim3(Ff / 128, MB, ksplit), 256, 0, stream>>>(
        h, W2T, b2, cnt, offs, list, wlist, out, Hc, kLen,
        c == nchunk - 1 ? 1 : 0);
  }
}

// Round 8
// 545.294 us; speedup vs baseline: 1.5049x; 1.5049x over previous
//
#include <hip/hip_runtime.h>
#include <hip/hip_bf16.h>

// Problem constants: B=4, S=1024, F=1024, E=8, K=2, H=4*F=4096
constexpr int Ff = 1024;
constexpr int Ee = 8;
constexpr int Hh = 4096;
constexpr int T  = 4096;        // B*S tokens
constexpr int MB = 72;          // 128-row m-blocks over padded row space (<= 9216 rows)

typedef short     bf16x8 __attribute__((ext_vector_type(8)));
typedef float     f32x4  __attribute__((ext_vector_type(4)));
typedef unsigned short u16x8 __attribute__((ext_vector_type(8)));

__device__ __forceinline__ float gelu_tanh(float v) {
  const float c = 0.7978845608028654f;  // sqrt(2/pi)
  float t = tanhf(c * (v + 0.044715f * v * v * v));
  return 0.5f * v * (1.0f + t);
}

__device__ __forceinline__ unsigned short bf16bits(float f) {
  __hip_bfloat16 h = __float2bfloat16(f);
  return *reinterpret_cast<unsigned short*>(&h);
}

__device__ __forceinline__ void gl_lds16(const void* g, void* l) {
  __builtin_amdgcn_global_load_lds(
      (const __attribute__((address_space(1))) unsigned int*)g,
      (__attribute__((address_space(3))) unsigned int*)l, 16, 0, 0);
}

// ---------------- Gating (fp32, exact routing) ----------------
__global__ __launch_bounds__(256) void gating_kernel(
    const float* __restrict__ x, const float* __restrict__ Wg,
    const float* __restrict__ bg, int* __restrict__ cnt,
    int* __restrict__ list, float* __restrict__ wlist) {
  const int wave = threadIdx.x >> 6;
  const int lane = threadIdx.x & 63;
  const int t = blockIdx.x * 4 + wave;
  float acc[Ee] = {0.f,0.f,0.f,0.f,0.f,0.f,0.f,0.f};
  const float* xrow = x + (size_t)t * Ff;
  for (int f0 = 0; f0 < Ff; f0 += 64) {
    float xv = xrow[f0 + lane];
    const float* wrow = Wg + (size_t)(f0 + lane) * Ee;
    float4 w0 = *reinterpret_cast<const float4*>(wrow);
    float4 w1 = *reinterpret_cast<const float4*>(wrow + 4);
    acc[0] += xv * w0.x; acc[1] += xv * w0.y;
    acc[2] += xv * w0.z; acc[3] += xv * w0.w;
    acc[4] += xv * w1.x; acc[5] += xv * w1.y;
    acc[6] += xv * w1.z; acc[7] += xv * w1.w;
  }
#pragma unroll
  for (int e = 0; e < Ee; ++e) {
#pragma unroll
    for (int off = 32; off; off >>= 1) acc[e] += __shfl_xor(acc[e], off);
  }
  if (lane == 0) {
    float l[Ee], m = -1e30f;
#pragma unroll
    for (int e = 0; e < Ee; ++e) { l[e] = acc[e] + bg[e]; m = fmaxf(m, l[e]); }
    float p[Ee], Z = 0.f;
#pragma unroll
    for (int e = 0; e < Ee; ++e) { p[e] = expf(l[e] - m); Z += p[e]; }
#pragma unroll
    for (int e = 0; e < Ee; ++e) p[e] /= Z;
    int i1 = 0; float p1 = p[0];
#pragma unroll
    for (int e = 1; e < Ee; ++e) if (p[e] > p1) { p1 = p[e]; i1 = e; }
    int i2 = -1; float p2 = -1e30f;
#pragma unroll
    for (int e = 0; e < Ee; ++e) if (e != i1 && p[e] > p2) { p2 = p[e]; i2 = e; }
    float denom = p1 + p2 + 1e-8f;
    int pos = atomicAdd(&cnt[i1], 1);
    list[i1 * T + pos] = t; wlist[i1 * T + pos] = p1 / denom;
    pos = atomicAdd(&cnt[i2], 1);
    list[i2 * T + pos] = t; wlist[i2 * T + pos] = p2 / denom;
  }
}

// 128-aligned expert row offsets (padded flattened row space)
__global__ void prefix_kernel(const int* __restrict__ cnt, int* __restrict__ offs) {
  if (threadIdx.x == 0) {
    int s = 0;
    for (int e = 0; e < Ee; ++e) { offs[e] = s; s += (cnt[e] + 127) & ~127; }
    offs[Ee] = s;
  }
}

// ---- pack_w: src fp32 [K][N] (row-major, stride sN) -> dst bf16 [NB][KT][4][128][8]
//      dst(nb,kt,kb,r,e) = src[kt*32+kb*8+e][nb*128+r].  grid (NB, KT, Ee), 256 thr
__global__ __launch_bounds__(256) void pack_w_kernel(
    const float* __restrict__ src, unsigned short* __restrict__ dst,
    int sN, size_t s_estride, size_t d_estride, int KT) {
  const int e  = blockIdx.z;
  const int nb = blockIdx.x;
  const int kt = blockIdx.y;
  __shared__ float Ts[128][33];
  const int t = threadIdx.x;
  const float* sb = src + (size_t)e * s_estride + (size_t)(kt * 32) * sN + nb * 128;
  {
    const int row = t >> 5;           // 0..7
    const int cc  = (t & 31) * 4;     // 0..124
#pragma unroll
    for (int i = 0; i < 4; ++i) {
      float4 v = *reinterpret_cast<const float4*>(sb + (size_t)(row + 8 * i) * sN + cc);
      Ts[cc + 0][row + 8 * i] = v.x;
      Ts[cc + 1][row + 8 * i] = v.y;
      Ts[cc + 2][row + 8 * i] = v.z;
      Ts[cc + 3][row + 8 * i] = v.w;
    }
  }
  __syncthreads();
  unsigned short* db = dst + (size_t)e * d_estride + ((size_t)nb * KT + kt) * 4096;
#pragma unroll
  for (int j = 0; j < 2; ++j) {
    const int idx = t + 256 * j;          // 0..511
    const int col = idx & 127, kb = idx >> 7;
    u16x8 o;
#pragma unroll
    for (int q = 0; q < 8; ++q) o[q] = bf16bits(Ts[col][kb * 8 + q]);
    *reinterpret_cast<u16x8*>(db + kb * 1024 + col * 8) = o;
  }
}

// ---- pack_x: gather tokens -> packed per-expert A: xg[mb][kt][4][128][8] (zeros for pads)
//      grid (Ff/32, MB), 256 thr
__global__ __launch_bounds__(256) void pack_x_kernel(
    const float* __restrict__ x, const int* __restrict__ cnt,
    const int* __restrict__ offs, const int* __restrict__ list,
    unsigned short* __restrict__ xg) {
  const int kt = blockIdx.x;
  const int mb = blockIdx.y;
  const int t = threadIdx.x;
  const int m0g = mb * 128;
  int e = 0;
#pragma unroll
  for (int i = 1; i < Ee; ++i) e += (m0g >= offs[i]) ? 1 : 0;
  const int ce = cnt[e];
  const int row = t >> 1, half = t & 1;
  const int mloc = m0g - offs[e] + row;
  const bool valid = (mloc < ce) && (mloc >= 0);
  const int token = valid ? list[e * T + mloc] : 0;
  const float* sp = x + (size_t)token * Ff + kt * 32 + half * 16;
  u16x8 o0, o1;
#pragma unroll
  for (int i = 0; i < 2; ++i) {
    float4 v = valid ? *reinterpret_cast<const float4*>(sp + i * 4)
                     : make_float4(0.f, 0.f, 0.f, 0.f);
    o0[i * 4 + 0] = bf16bits(v.x); o0[i * 4 + 1] = bf16bits(v.y);
    o0[i * 4 + 2] = bf16bits(v.z); o0[i * 4 + 3] = bf16bits(v.w);
  }
#pragma unroll
  for (int i = 2; i < 4; ++i) {
    float4 v = valid ? *reinterpret_cast<const float4*>(sp + i * 4)
                     : make_float4(0.f, 0.f, 0.f, 0.f);
    o1[(i - 2) * 4 + 0] = bf16bits(v.x); o1[(i - 2) * 4 + 1] = bf16bits(v.y);
    o1[(i - 2) * 4 + 2] = bf16bits(v.z); o1[(i - 2) * 4 + 3] = bf16bits(v.w);
  }
  unsigned short* db = xg + ((size_t)mb * (Ff / 32) + kt) * 4096 + row * 8;
  *reinterpret_cast<u16x8*>(db + (half * 2 + 0) * 1024) = o0;
  *reinterpret_cast<u16x8*>(db + (half * 2 + 1) * 1024) = o1;
}

// ======== GEMM1: h = gelu(xg @ W1P^T + b1) — packed operands, contiguous staging ========
__global__ __launch_bounds__(256) void gemm1_mfma(
    const unsigned short* __restrict__ xg, const unsigned short* __restrict__ W1P,
    const float* __restrict__ b1, const int* __restrict__ cnt,
    const int* __restrict__ offs, const int* __restrict__ list,
    unsigned short* __restrict__ hp, int Hc, int c) {
  const int nxg = Hc >> 7;
  const int nwg = nxg * MB;
  int raw = blockIdx.x + nxg * blockIdx.y;
  int bid = (raw & 7) * (nwg >> 3) + (raw >> 3);
  const int bx = bid % nxg, by = bid / nxg;
  const int m0g = by * 128;
  int e = 0;
#pragma unroll
  for (int i = 1; i < Ee; ++i) e += (m0g >= offs[i]) ? 1 : 0;
  const int ce = cnt[e];
  const int mloc = m0g - offs[e];
  if (mloc >= ce) return;
  const int n0 = bx * 128;

  __shared__ __align__(16) unsigned short As[2][4][128][8];
  __shared__ __align__(16) unsigned short Bs[2][4][128][8];
  const int tid = threadIdx.x;
  const int w = tid >> 6, lane = tid & 63;
  const int g = lane >> 4, r16 = lane & 15;
  const int wr = w >> 1, wc = w & 1;
  constexpr int KT = Ff / 32;   // 32

  const unsigned short* aBase = xg + (size_t)by * KT * 4096 + w * 1024 + lane * 8;
  const unsigned short* bBase = W1P + ((size_t)(e * nxg + bx) * KT) * 4096 + w * 1024 + lane * 8;

  f32x4 acc[4][4] = {};
  auto STAGE = [&](int buf, int kt) {
    unsigned short* aD = &As[buf][0][0][0] + w * 1024;
    unsigned short* bD = &Bs[buf][0][0][0] + w * 1024;
    const size_t ko = (size_t)kt * 4096;
    gl_lds16(aBase + ko, aD);
    gl_lds16(aBase + ko + 512, aD + 512);
    gl_lds16(bBase + ko, bD);
    gl_lds16(bBase + ko + 512, bD + 512);
  };
  STAGE(0, 0);
  int cur = 0;
#pragma unroll 1
  for (int kt = 0; kt < KT; ++kt) {
    if (kt + 1 < KT) {
      STAGE(cur ^ 1, kt + 1);
      asm volatile("s_waitcnt vmcnt(4)" ::: "memory");
    } else {
      asm volatile("s_waitcnt vmcnt(0)" ::: "memory");
    }
    __builtin_amdgcn_s_barrier();
    asm volatile("" ::: "memory");
    bf16x8 af[4], bfr[4];
#pragma unroll
    for (int i = 0; i < 4; ++i) {
      af[i]  = *reinterpret_cast<const bf16x8*>(&As[cur][g][wr * 64 + i * 16 + r16][0]);
      bfr[i] = *reinterpret_cast<const bf16x8*>(&Bs[cur][g][wc * 64 + i * 16 + r16][0]);
    }
    __builtin_amdgcn_s_setprio(1);
#pragma unroll
    for (int mi = 0; mi < 4; ++mi)
#pragma unroll
      for (int ni = 0; ni < 4; ++ni)
        acc[mi][ni] = __builtin_amdgcn_mfma_f32_16x16x32_bf16(
            af[mi], bfr[ni], acc[mi][ni], 0, 0, 0);
    __builtin_amdgcn_s_setprio(0);
    asm volatile("" ::: "memory");
    __builtin_amdgcn_s_barrier();
    cur ^= 1;
  }
  // epilogue: write h in gemm2's packed-A layout hp[mb][kt2][kb][row][8]
  const int KT2 = Hc >> 5;
  unsigned short* hb = hp + (size_t)by * KT2 * 4096;
#pragma unroll
  for (int ni = 0; ni < 4; ++ni) {
    const int col = n0 + wc * 64 + ni * 16 + r16;
    const float bias = b1[(size_t)e * Hh + (size_t)c * Hc + col];
    unsigned short* hcol = hb + (((size_t)(col >> 5) * 4 + ((col >> 3) & 3)) * 1024 + (col & 7));
#pragma unroll
    for (int mi = 0; mi < 4; ++mi)
#pragma unroll
      for (int r = 0; r < 4; ++r) {
        const int row = wr * 64 + mi * 16 + g * 4 + r;
        if (mloc + row < ce)
          hcol[row * 8] = bf16bits(gelu_tanh(acc[mi][ni][r] + bias));
      }
  }
}

// ==== GEMM2: out += w * (hp @ W2P^T (+b2)) — packed operands, K-split ====
__global__ __launch_bounds__(256) void gemm2_mfma(
    const unsigned short* __restrict__ hp, const unsigned short* __restrict__ W2P,
    const float* __restrict__ b2, const int* __restrict__ cnt,
    const int* __restrict__ offs, const int* __restrict__ list,
    const float* __restrict__ wlist, float* __restrict__ out,
    int Hc, int kLen, int ksplit, int biasC) {
  const int nxg = Ff >> 7;   // 8
  const int nwg = nxg * MB * ksplit;
  int raw = blockIdx.x + nxg * (blockIdx.y + MB * blockIdx.z);
  int bid = (raw & 7) * (nwg >> 3) + (raw >> 3);
  const int bx = bid % nxg;
  const int rest = bid / nxg;
  const int by = rest % MB, bz = rest / MB;

  const int m0g = by * 128;
  int e = 0;
#pragma unroll
  for (int i = 1; i < Ee; ++i) e += (m0g >= offs[i]) ? 1 : 0;
  const int ce = cnt[e];
  const int mloc = m0g - offs[e];
  if (mloc >= ce) return;
  const int n0 = bx * 128;

  __shared__ __align__(16) unsigned short As[2][4][128][8];
  __shared__ __align__(16) unsigned short Bs[2][4][128][8];
  const int tid = threadIdx.x;
  const int w = tid >> 6, lane = tid & 63;
  const int g = lane >> 4, r16 = lane & 15;
  const int wr = w >> 1, wc = w & 1;
  const int KT2 = Hc >> 5;
  const int ktOff = (bz * kLen) >> 5;
  const int NT = kLen >> 5;

  const unsigned short* aBase = hp + ((size_t)by * KT2 + ktOff) * 4096 + w * 1024 + lane * 8;
  const unsigned short* bBase = W2P + (((size_t)(e * nxg + bx)) * KT2 + ktOff) * 4096 + w * 1024 + lane * 8;

  f32x4 acc[4][4] = {};
  auto STAGE = [&](int buf, int kt) {
    unsigned short* aD = &As[buf][0][0][0] + w * 1024;
    unsigned short* bD = &Bs[buf][0][0][0] + w * 1024;
    const size_t ko = (size_t)kt * 4096;
    gl_lds16(aBase + ko, aD);
    gl_lds16(aBase + ko + 512, aD + 512);
    gl_lds16(bBase + ko, bD);
    gl_lds16(bBase + ko + 512, bD + 512);
  };
  STAGE(0, 0);
  int cur = 0;
#pragma unroll 1
  for (int kt = 0; kt < NT; ++kt) {
    if (kt + 1 < NT) {
      STAGE(cur ^ 1, kt + 1);
      asm volatile("s_waitcnt vmcnt(4)" ::: "memory");
    } else {
      asm volatile("s_waitcnt vmcnt(0)" ::: "memory");
    }
    __builtin_amdgcn_s_barrier();
    asm volatile("" ::: "memory");
    bf16x8 af[4], bfr[4];
#pragma unroll
    for (int i = 0; i < 4; ++i) {
      af[i]  = *reinterpret_cast<const bf16x8*>(&As[cur][g][wr * 64 + i * 16 + r16][0]);
      bfr[i] = *reinterpret_cast<const bf16x8*>(&Bs[cur][g][wc * 64 + i * 16 + r16][0]);
    }
    __builtin_amdgcn_s_setprio(1);
#pragma unroll
    for (int mi = 0; mi < 4; ++mi)
#pragma unroll
      for (int ni = 0; ni < 4; ++ni)
        acc[mi][ni] = __builtin_amdgcn_mfma_f32_16x16x32_bf16(
            af[mi], bfr[ni], acc[mi][ni], 0, 0, 0);
    __builtin_amdgcn_s_setprio(0);
    asm volatile("" ::: "memory");
    __builtin_amdgcn_s_barrier();
    cur ^= 1;
  }
  const bool addBias = (biasC != 0) && (bz == 0);
#pragma unroll
  for (int mi = 0; mi < 4; ++mi)
#pragma unroll
    for (int r = 0; r < 4; ++r) {
      const int row = wr * 64 + mi * 16 + g * 4 + r;
      if (mloc + row >= ce) continue;
      const int token = list[e * T + mloc + row];
      const float wgt = wlist[e * T + mloc + row];
      float* op = out + (size_t)token * Ff;
#pragma unroll
      for (int ni = 0; ni < 4; ++ni) {
        const int col = n0 + wc * 64 + ni * 16 + r16;
        float v = acc[mi][ni][r];
        if (addBias) v += b2[(size_t)e * Ff + col];
        atomicAdd(&op[col], wgt * v);
      }
    }
}

extern "C" void kernel_launch(void* const* d_in, const int* in_sizes, int n_in,
                              void* d_out, int out_size, void* d_ws, size_t ws_size,
                              hipStream_t stream) {
  const float* x  = (const float*)d_in[0];
  const float* Wg = (const float*)d_in[1];
  const float* bg = (const float*)d_in[2];
  const float* W1 = (const float*)d_in[3];
  const float* b1 = (const float*)d_in[4];
  const float* W2 = (const float*)d_in[5];
  const float* b2 = (const float*)d_in[6];
  float* out = (float*)d_out;

  // fixed = ctrl + lists + xg(9216 x 1024 bf16 packed); per-Hc-unit = W1P + W2P + hp
  const size_t fixed = 1024 + 2 * (size_t)T * Ee * 4 + (size_t)MB * 128 * Ff * 2;
  int Hc = 4096;
  while (Hc > 256 && fixed + (size_t)Hc * 51200 > ws_size) Hc >>= 1;
  const int nchunk = Hh / Hc;
  const int ksplit = 4;
  const int kLen = Hc / ksplit;   // >= 64

  char* p = (char*)d_ws;
  int*   cnt   = (int*)p;            p += 512;
  int*   offs  = (int*)p;            p += 512;
  int*   list  = (int*)p;            p += (size_t)T * Ee * 4;
  float* wlist = (float*)p;          p += (size_t)T * Ee * 4;
  unsigned short* xg  = (unsigned short*)p;  p += (size_t)MB * 128 * Ff * 2;
  unsigned short* W1P = (unsigned short*)p;  p += (size_t)Ee * Hc * Ff * 2;
  unsigned short* W2P = (unsigned short*)p;  p += (size_t)Ee * Ff * Hc * 2;
  unsigned short* hp  = (unsigned short*)p;  // MB*128 * Hc * 2

  hipMemsetAsync(d_out, 0, (size_t)out_size * sizeof(float), stream);
  hipMemsetAsync(cnt, 0, 64, stream);

  gating_kernel<<<T / 4, 256, 0, stream>>>(x, Wg, bg, cnt, list, wlist);
  prefix_kernel<<<1, 64, 0, stream>>>(cnt, offs);
  pack_x_kernel<<<dim3(Ff / 32, MB), 256, 0, stream>>>(x, cnt, offs, list, xg);

  for (int c = 0; c < nchunk; ++c) {
    // W1 chunk: K=Ff rows, N cols = [c*Hc, c*Hc+Hc)
    pack_w_kernel<<<dim3(Hc / 128, Ff / 32, Ee), 256, 0, stream>>>(
        W1 + (size_t)c * Hc, W1P, Hh, (size_t)Ff * Hh, (size_t)Hc * Ff, Ff / 32);
    // W2 chunk: K rows = [c*Hc, c*Hc+Hc), N = Ff cols
    pack_w_kernel<<<dim3(Ff / 128, Hc / 32, Ee), 256, 0, stream>>>(
        W2 + (size_t)c * Hc * Ff, W2P, Ff, (size_t)Hh * Ff, (size_t)Ff * Hc, Hc / 32);
    gemm1_mfma<<<dim3(Hc / 128, MB), 256, 0, stream>>>(
        xg, W1P, b1, cnt, offs, list, hp, Hc, c);
    gemm2_mfma<<<dim3(Ff / 128, MB, ksplit), 256, 0, stream>>>(
        hp, W2P, b2, cnt, offs, list, wlist, out, Hc, kLen, ksplit,
        c == nchunk - 1 ? 1 : 0);
  }
}